// Round 12
// baseline (4592.870 us; speedup 1.0000x reference)
//
#include <hip/hip_runtime.h>
#include <math.h>

// Point-MAE Group — FPS(2048) + kNN(16) + gather/subtract.
// B=4, N=16384, G=2048, M=16.
// NUMERICS CONTRACT (verified absmax=0.0 in rounds 4-11 — do not change):
//  - FPS: d = ((dx*dx)+(dy*dy))+(dz*dz), all separate f32 ops, no FMA
//    (packed VOP3P ops are two independent IEEE f32 lanes — proven r11;
//    x + (-p) == x - p exactly).
//  - kNN: d2 = (cc - 2*dot) + xx; ONLY dot is an FMA chain (numpy einsum).
//  - FPS argmax: first occurrence of max; top-16: stable ascending order.
//
// Round-12: r11 showed VALU issue fell 21% with zero time change -> the
// ~3000cy/iter fixed cost is the SERIAL REDUCTION TAIL (u64 shuffle butterfly,
// dependent eq-scan, LDS round trips), not issue throughput. This round:
//  - CONTIGUOUS ownership (thread t owns [32t,32t+32)) makes
//    (max value, lowest lane, lowest local j) == global first-max, so the
//    reduce needs only f32 v_max butterfly + one ballot + ffs. No u64 keys.
//  - per-thread first-max eq-scan (carrying winner z) overlaps the butterfly
//    (independent dep chains). Static register indexing only.
//  - ONE barrier: lane0 stores (wm, z, idx) float4; all threads scan 8 f32,
//    winner (x,y) via broadcast ds_read from pair-transposed XP/YP
//    ([j*512+t] storage, bank-conflict-free — r11-proven).

#pragma clang fp contract(off)

#define N_PTS 16384
#define N_GROUP 2048
#define GROUP_SIZE 16
#define FPS_THREADS 512
#define NPAIR 16                      // 32 points = 16 packed pairs per thread
#define FPS_WAVES (FPS_THREADS / 64)
#define KNN_THREADS 256
#define KNN_WAVES (KNN_THREADS / 64)

// a*b as a standalone instruction (kNN only — keep the exact passing form).
__device__ __forceinline__ float fmul_sep(float a, float b) {
  float r = a * b;
  asm volatile("" : "+v"(r));
  return r;
}

__device__ __forceinline__ float2 pk_add(float2 a, float2 b) {
  float2 d;
  asm("v_pk_add_f32 %0, %1, %2" : "=v"(d) : "v"(a), "v"(b));
  return d;
}
__device__ __forceinline__ float2 pk_sq(float2 a) {
  float2 d;
  asm("v_pk_mul_f32 %0, %1, %1" : "=v"(d) : "v"(a));
  return d;
}

// ---------------------------------------------------------------------------
// FPS: one block per batch. XP/YP pair-transposed in LDS, Z/MD in registers.
// Ownership contiguous: thread t owns points 32t..32t+31 (pair j = 2j,2j+1).
// ---------------------------------------------------------------------------
__global__ __launch_bounds__(FPS_THREADS)
__attribute__((amdgpu_waves_per_eu(2, 2)))
void fps_kernel(const float* __restrict__ pcd, float* __restrict__ center) {
#pragma clang fp contract(off)
  const int b = blockIdx.x;
  const int t = threadIdx.x;
  const int lane = t & 63;
  const int wid = t >> 6;
  const float* xyz = pcd + (size_t)b * N_PTS * 3;

  __shared__ float2 XP[NPAIR * FPS_THREADS];  // 64 KiB, [j*512 + t]
  __shared__ float2 YP[NPAIR * FPS_THREADS];  // 64 KiB
  __shared__ float4 sres[2][FPS_WAVES];       // (wm, z, idx-bits, pad)

  float2 Z[NPAIR], MD[NPAIR];
#pragma unroll
  for (int j = 0; j < NPAIR; ++j) {
    const int i0 = t * 32 + 2 * j;            // contiguous ownership
    XP[j * FPS_THREADS + t] = make_float2(xyz[i0 * 3 + 0], xyz[i0 * 3 + 3]);
    YP[j * FPS_THREADS + t] = make_float2(xyz[i0 * 3 + 1], xyz[i0 * 3 + 4]);
    Z[j] = make_float2(xyz[i0 * 3 + 2], xyz[i0 * 3 + 5]);
    MD[j] = make_float2(1e10f, 1e10f);
  }
#pragma unroll
  for (int j = 0; j < NPAIR; ++j) asm("" : "+v"(Z[j]));  // forbid remat/spill games

  float px = xyz[0], py = xyz[1], pz = xyz[2];
  if (t == 0) {
    center[((size_t)b * N_GROUP) * 3 + 0] = px;
    center[((size_t)b * N_GROUP) * 3 + 1] = py;
    center[((size_t)b * N_GROUP) * 3 + 2] = pz;
  }
  __syncthreads();  // XP/YP ready

  for (int it = 1; it < N_GROUP; ++it) {
    const int p = it & 1;
    const float2 npx2 = make_float2(-px, -px);
    const float2 npy2 = make_float2(-py, -py);
    const float2 npz2 = make_float2(-pz, -pz);
    float bv = -1.0f;
#pragma unroll
    for (int j = 0; j < NPAIR; ++j) {
      const float2 dx = pk_add(XP[j * FPS_THREADS + t], npx2);  // x + (-px)
      const float2 dy = pk_add(YP[j * FPS_THREADS + t], npy2);
      const float2 dz = pk_add(Z[j], npz2);
      const float2 s = pk_add(pk_add(pk_sq(dx), pk_sq(dy)), pk_sq(dz));
      MD[j].x = fminf(MD[j].x, s.x);
      MD[j].y = fminf(MD[j].y, s.y);
      bv = fmaxf(bv, MD[j].x);
      bv = fmaxf(bv, MD[j].y);
    }

    // Per-thread first-max (lowest j) + winner z, as an independent dep chain
    // that overlaps the value butterfly below (both only need bv).
    int ii = 0;
    float zw = Z[0].x;
#pragma unroll
    for (int j = NPAIR - 1; j >= 0; --j) {
      if (MD[j].y == bv) { ii = 2 * j + 1; zw = Z[j].y; }
      if (MD[j].x == bv) { ii = 2 * j;     zw = Z[j].x; }
    }

    // Wave value-only max butterfly (f32 v_max per step).
    float wm = bv;
#pragma unroll
    for (int off = 32; off > 0; off >>= 1) wm = fmaxf(wm, __shfl_xor(wm, off));

    // First lane achieving wm == lowest point index in this wave
    // (contiguous ownership: lane order == index order).
    const unsigned long long mask = __ballot(bv == wm);
    const int wl = __ffsll(mask) - 1;                 // wave-uniform
    const int widx = (wid * 64 + wl) * 32 + __shfl(ii, wl);
    const float wz = __shfl(zw, wl);
    if (lane == 0)
      sres[p][wid] = make_float4(wm, wz, __int_as_float(widx), 0.0f);
    __syncthreads();

    // Cross-wave: ascending scan, strict > keeps the first (lowest) wave.
    float4 r0 = sres[p][0];
    float bb = r0.x; int bw = 0;
#pragma unroll
    for (int j = 1; j < FPS_WAVES; ++j) {
      const float vj = sres[p][j].x;
      if (vj > bb) { bb = vj; bw = j; }
    }
    const float4 win = sres[p][bw];
    const int idx = __float_as_int(win.z);
    pz = win.y;
    const int tw = idx >> 5, iw = idx & 31, jw = iw >> 1, k = iw & 1;
    const float2 qx = XP[jw * FPS_THREADS + tw];      // broadcast read
    const float2 qy = YP[jw * FPS_THREADS + tw];      // broadcast read
    px = k ? qx.y : qx.x;
    py = k ? qy.y : qy.x;
    if (t == 0) {
      center[((size_t)b * N_GROUP + it) * 3 + 0] = px;
      center[((size_t)b * N_GROUP + it) * 3 + 1] = py;
      center[((size_t)b * N_GROUP + it) * 3 + 2] = pz;
    }
    // single barrier/iter: double-buffered sres fences reuse at it+2.
  }
}

// ---------------------------------------------------------------------------
// kNN: one wave per center; lanes 0..15 hold the sorted top-16.
// d2 = (cc - 2*dot) + xx; cc/xx separate ops; dot = FMA chain (einsum).
// (unchanged from the bit-exact round-4 version)
// ---------------------------------------------------------------------------
__global__ __launch_bounds__(KNN_THREADS) void knn_kernel(
    const float* __restrict__ pcd, const float* __restrict__ center,
    float* __restrict__ nbr) {
#pragma clang fp contract(off)
  const int lane = threadIdx.x & 63;
  const int gw = blockIdx.x * KNN_WAVES + (threadIdx.x >> 6);  // center id
  const int b = gw >> 11;                                      // G = 2048
  const float* xyz = pcd + (size_t)b * N_PTS * 3;

  const float c0 = center[(size_t)gw * 3 + 0];
  const float c1 = center[(size_t)gw * 3 + 1];
  const float c2 = center[(size_t)gw * 3 + 2];
  const float cc = (fmul_sep(c0, c0) + fmul_sep(c1, c1)) + fmul_sep(c2, c2);

  float lval = INFINITY;  // lanes 0..15: sorted list values (ascending)
  int lidx = 0;
  float worst = INFINITY; // 16th-smallest so far, wave-uniform

  for (int ch = 0; ch < N_PTS / 64; ++ch) {
    const int n = ch * 64 + lane;
    const float xp = xyz[n * 3 + 0];
    const float yp = xyz[n * 3 + 1];
    const float zp = xyz[n * 3 + 2];
    const float xx = (fmul_sep(xp, xp) + fmul_sep(yp, yp)) + fmul_sep(zp, zp);
    // numpy einsum: acc=0; acc=fma(c0,x,acc); acc=fma(c1,y,acc); acc=fma(c2,z,acc)
    const float dot = fmaf(c2, zp, fmaf(c1, yp, c0 * xp));
    const float d2 = (cc - fmul_sep(2.0f, dot)) + xx;

    unsigned long long m = __ballot(d2 < worst);
    while (m) {
      const int srcl = __ffsll((unsigned long long)m) - 1;  // ascending index
      m &= (m - 1);
      const float nv = __shfl(d2, srcl);
      if (nv < worst) {  // wave-uniform decision
        const int ni = ch * 64 + srcl;
        const int rank = __popcll(__ballot(lane < GROUP_SIZE && lval <= nv));
        const float shv = __shfl_up(lval, 1);
        const int   shi = __shfl_up(lidx, 1);
        if (lane < GROUP_SIZE) {
          if (lane == rank)      { lval = nv;  lidx = ni;  }
          else if (lane > rank)  { lval = shv; lidx = shi; }
        }
        worst = __shfl(lval, 15);
      }
    }
  }

  if (lane < GROUP_SIZE) {
    const float ox = xyz[lidx * 3 + 0] - c0;
    const float oy = xyz[lidx * 3 + 1] - c1;
    const float oz = xyz[lidx * 3 + 2] - c2;
    const size_t o = ((size_t)gw * GROUP_SIZE + lane) * 3;
    nbr[o + 0] = ox; nbr[o + 1] = oy; nbr[o + 2] = oz;
  }
}

extern "C" void kernel_launch(void* const* d_in, const int* in_sizes, int n_in,
                              void* d_out, int out_size, void* d_ws, size_t ws_size,
                              hipStream_t stream) {
  const float* pcd = (const float*)d_in[0];
  const int B = in_sizes[0] / (N_PTS * 3);  // = 4

  float* out = (float*)d_out;
  float* nbr = out;                                            // B*G*M*3
  float* center = out + (size_t)B * N_GROUP * GROUP_SIZE * 3;  // B*G*3

  fps_kernel<<<B, FPS_THREADS, 0, stream>>>(pcd, center);
  knn_kernel<<<(B * N_GROUP) / KNN_WAVES, KNN_THREADS, 0, stream>>>(pcd, center, nbr);
}